// Round 15
// baseline (217.798 us; speedup 1.0000x reference)
//
#include <hip/hip_runtime.h>
#include <math.h>

#define N_BINS 229
#define MODEL  128
#define OUTD   88
#define WSZ    30
#define WLEN   61
#define BB     4
#define TT     2048
#define CTANH  2.8853900817779268f   // 2*log2(e)

#define ROWS_HE 8
#define SPAD2   256                  // zero-padded spec row stride (floats)
#define WCOLS   344                  // H 128 | E 128 | S1 88
#define CHUNK   32                   // f per W tile

#define ROWS_F  8                    // rows per fused block (1 wave per row)
#define FHALO   71                   // hi = wv + w, wv<8, w<64 -> 0..70
#define EPADU   68                   // u32 stride per E halo row

__device__ __forceinline__ float sigmoidf_(float x) {
    return __builtin_amdgcn_rcpf(1.0f + __expf(-x));
}

// ---- Pass 1: H=(spec@W_h+b)*C ; Ebf=bf16(spec@W_e*C) ; S1=spec@W1 ----
// 384 threads, 8 rows/block. W staged in 32-f LDS chunks: per-thread column
// reads are stride-1 b32 (conflict-free, full LDS BW); spec b128 broadcasts
// drop to 8 per 32 FMAs. VGPR ~35, no spill (launch_bounds cap 128).
__global__ __launch_bounds__(384, 4) void k_he(
        const float* __restrict__ spec,
        const float* __restrict__ W_h,
        const float* __restrict__ W_e,
        const float* __restrict__ W1,
        const float* __restrict__ b_attn,
        float* __restrict__ H,
        unsigned int* __restrict__ Ebf,
        float* __restrict__ S1) {
    const int nb  = blockIdx.x;
    const int tid = threadIdx.x;
    __shared__ float s[ROWS_HE * SPAD2];               //  8192 B
    __shared__ float Wt[CHUNK * WCOLS];                // 44032 B (total ~52 KB)

    const float* __restrict__ base = spec + (size_t)nb * (ROWS_HE * N_BINS);
    for (int i = tid; i < ROWS_HE * SPAD2; i += 384) {
        const int r = i >> 8, f = i & 255;
        s[i] = (f < N_BINS) ? base[r * N_BINS + f] : 0.0f;
    }

    const int col = (tid < WCOLS) ? tid : (WCOLS - 1);
    const int m   = (tid < 128) ? tid : (tid < 256) ? tid - 128 : col - 256;
    const float bias = (tid < 128) ? b_attn[m] : 0.0f;

    float acc[ROWS_HE];
#pragma unroll
    for (int r = 0; r < ROWS_HE; ++r) acc[r] = 0.0f;

    const float4* __restrict__ Wh4 = (const float4*)W_h;   // 32 f4 per row
    const float4* __restrict__ We4 = (const float4*)W_e;   // 32 f4 per row
    const float4* __restrict__ W14 = (const float4*)W1;    // 22 f4 per row

    for (int ck = 0; ck < 8; ++ck) {                   // 8*32 = 256 f (padded)
        const int fb = ck * CHUNK;
        __syncthreads();                               // protect Wt from last use
        for (int idx = tid; idx < CHUNK * 86; idx += 384) {
            const int f  = idx / 86;
            const int c4 = idx - f * 86;
            const int gf = fb + f;
            float4 v = make_float4(0.f, 0.f, 0.f, 0.f);
            if (gf < N_BINS) {
                if (c4 < 32)      v = Wh4[gf * 32 + c4];
                else if (c4 < 64) v = We4[gf * 32 + (c4 - 32)];
                else              v = W14[gf * 22 + (c4 - 64)];
            }
            *(float4*)&Wt[f * WCOLS + (c4 << 2)] = v;
        }
        __syncthreads();

#pragma unroll
        for (int j4 = 0; j4 < 8; ++j4) {               // 4 f per step
            const int fl = j4 << 2;
            const float w0 = Wt[(fl + 0) * WCOLS + col];
            const float w1 = Wt[(fl + 1) * WCOLS + col];
            const float w2 = Wt[(fl + 2) * WCOLS + col];
            const float w3 = Wt[(fl + 3) * WCOLS + col];
#pragma unroll
            for (int r = 0; r < ROWS_HE; ++r) {
                const float4 sa = *(const float4*)&s[r * SPAD2 + fb + fl];
                acc[r] = fmaf(sa.x, w0, acc[r]);
                acc[r] = fmaf(sa.y, w1, acc[r]);
                acc[r] = fmaf(sa.z, w2, acc[r]);
                acc[r] = fmaf(sa.w, w3, acc[r]);
            }
        }
    }

    const int rg0 = nb * ROWS_HE;
    if (tid < 128) {
#pragma unroll
        for (int r = 0; r < ROWS_HE; ++r)
            H[(size_t)(rg0 + r) * MODEL + m] = (acc[r] + bias) * CTANH;
    } else if (tid < 256) {
#pragma unroll
        for (int r = 0; r < ROWS_HE; ++r) {
            const float val = acc[r] * CTANH;              // pre-scaled E
            const float pv  = __shfl_xor(val, 1, 64);
            if ((m & 1) == 0) {                            // even m packs (m, m+1)
                const unsigned int lo = (__float_as_uint(val) + 0x8000u) >> 16;
                const unsigned int hi = (__float_as_uint(pv) + 0x8000u) & 0xFFFF0000u;
                Ebf[(size_t)(rg0 + r) * 64 + (m >> 1)] = hi | lo;
            }
        }
    } else if (tid < 256 + OUTD) {
#pragma unroll
        for (int r = 0; r < ROWS_HE; ++r)
            S1[(size_t)(rg0 + r) * OUTD + m] = acc[r];     // b1 added later
    }
}

// ---- Pass 2 (fused, round-11-exact: measured 62 us): scores + softmax +
// 88-dim pooling + sigmoid. 512 threads = 8 waves = 8 rows, 1024 blocks.
__global__ __launch_bounds__(512, 8) void k_fused(
        const float* __restrict__ H,
        const unsigned int* __restrict__ Ebf,
        const float* __restrict__ v_w,
        const float* __restrict__ S1,
        const float* __restrict__ b1,
        float* __restrict__ pred,
        float* __restrict__ a_out) {
    const int nb   = blockIdx.x;
    const int tid  = threadIdx.x;
    const int wv   = tid >> 6;              // 0..7 = local row
    const int lane = tid & 63;
    const int r0   = nb * ROWS_F;
    const int b    = r0 >> 11;              // T = 2048
    const int t0   = r0 & (TT - 1);
    const int r    = r0 + wv;
    const int t    = t0 + wv;

    __shared__ __align__(16) unsigned char ubuf[FHALO * OUTD * 4];  // 24992 B
    unsigned int* Ebs = (unsigned int*)ubuf;        // [FHALO][EPADU]
    float*        S1h = (float*)ubuf;               // [FHALO][88]
    __shared__ float4 Hs4[ROWS_F * 32];             //  4096 B
    __shared__ float4 Vs4[32];                      //   512 B
    __shared__ float  scA[ROWS_F][64];              //  2048 B
    __shared__ float  cf[ROWS_F][64];               //  2048 B (total ~33.7 KB)

    // ---- stage bf16 E halo (zero outside [0,TT) == reference zero-pad) ----
    const uint4* __restrict__ Eb16 = (const uint4*)Ebf + (size_t)b * TT * 16;
    for (int i = tid; i < FHALO * 16; i += 512) {
        const int row = i >> 4, c = i & 15;
        const int s   = t0 - WSZ + row;
        uint4 v = make_uint4(0u, 0u, 0u, 0u);
        if (s >= 0 && s < TT) v = Eb16[(size_t)s * 16 + c];
        *(uint4*)&Ebs[row * EPADU + (c << 2)] = v;
    }
    if (tid < ROWS_F * 32)
        Hs4[tid] = ((const float4*)H)[(size_t)r0 * 32 + tid];
    else if (tid < ROWS_F * 32 + 32)
        Vs4[tid - ROWS_F * 32] = ((const float4*)v_w)[tid - ROWS_F * 32];
    __syncthreads();

    const int g  = lane & 3;
    const int w0 = lane >> 2;

    // ---- Sum(v_w), hoisted ----
    float vs = 0.f;
#pragma unroll
    for (int q = 0; q < 8; ++q) {
        const float4 vq = Vs4[(q << 2) + g];
        vs += (vq.x + vq.y) + (vq.z + vq.w);
    }
    vs += __shfl_xor(vs, 1, 64);
    vs += __shfl_xor(vs, 2, 64);

    // ---- scores for row wv ----
    int ro[4];
#pragma unroll
    for (int it = 0; it < 4; ++it)
        ro[it] = (wv + w0 + it * 16) * EPADU;       // hi in [0,70]

    const float4* __restrict__ HsR = &Hs4[wv * 32];

    float pp[4] = {0.f, 0.f, 0.f, 0.f};
#pragma unroll
    for (int q = 0; q < 8; ++q) {
        const int    cq = (q << 2) + g;
        const float4 hq = HsR[cq];          // pre-scaled by CTANH
        const float4 vq = Vs4[cq];
        const float nx = -2.f * vq.x, ny = -2.f * vq.y,
                    nz = -2.f * vq.z, nw = -2.f * vq.w;
#pragma unroll
        for (int it = 0; it < 4; ++it) {
            const uint2 e2 = *(const uint2*)&Ebs[ro[it] + (cq << 1)];
            const float f0 = __uint_as_float(e2.x << 16);
            const float f1 = __uint_as_float(e2.x & 0xFFFF0000u);
            const float f2 = __uint_as_float(e2.y << 16);
            const float f3 = __uint_as_float(e2.y & 0xFFFF0000u);
            float u;
            u = __builtin_amdgcn_rcpf(__builtin_amdgcn_exp2f(f0 + hq.x) + 1.f);
            pp[it] = fmaf(nx, u, pp[it]);
            u = __builtin_amdgcn_rcpf(__builtin_amdgcn_exp2f(f1 + hq.y) + 1.f);
            pp[it] = fmaf(ny, u, pp[it]);
            u = __builtin_amdgcn_rcpf(__builtin_amdgcn_exp2f(f2 + hq.z) + 1.f);
            pp[it] = fmaf(nz, u, pp[it]);
            u = __builtin_amdgcn_rcpf(__builtin_amdgcn_exp2f(f3 + hq.w) + 1.f);
            pp[it] = fmaf(nw, u, pp[it]);
        }
    }
#pragma unroll
    for (int it = 0; it < 4; ++it) {
        float p = pp[it];
        p += __shfl_xor(p, 1, 64);
        p += __shfl_xor(p, 2, 64);
        const int w = w0 + it * 16;
        if (g == 0 && w < WLEN) scA[wv][w] = p + vs;
    }

    // ---- wave-local softmax (same wave wrote scA[wv]) ----
    {
        float x = (lane < WLEN) ? scA[wv][lane] : -INFINITY;
        float mx = x;
#pragma unroll
        for (int d = 32; d >= 1; d >>= 1) mx = fmaxf(mx, __shfl_xor(mx, d, 64));
        float e = (lane < WLEN) ? __expf(x - mx) : 0.0f;
        float sm = e;
#pragma unroll
        for (int d = 32; d >= 1; d >>= 1) sm += __shfl_xor(sm, d, 64);
        const float a = e * __builtin_amdgcn_rcpf(sm);
        if (lane < WLEN) a_out[(size_t)r * WLEN + lane] = a;
        const int sl = t + lane - WSZ;
        cf[wv][lane] = (lane < WLEN && sl >= 0 && sl < TT) ? a : 0.0f;
    }

    __syncthreads();                        // all waves done reading Ebs

    // ---- re-stage union with S1 halo (zero outside [0,TT)) ----
    const float4* __restrict__ Sb4 = (const float4*)S1 + (size_t)b * TT * 22;
    for (int i = tid; i < FHALO * 22; i += 512) {
        const int row = i / 22, c = i - row * 22;
        const int s   = t0 - WSZ + row;
        float4 v = make_float4(0.f, 0.f, 0.f, 0.f);
        if (s >= 0 && s < TT) v = Sb4[(size_t)s * 22 + c];
        *(float4*)&S1h[row * OUTD + (c << 2)] = v;
    }
    __syncthreads();

    // ---- pooling row wv: pred[t] = sigmoid(sum_w cf[w]*S1h[wv+w] + b1) ----
    const int o2 = 64 + (lane < 24 ? lane : 23);
    float a1 = 0.f, a2 = 0.f;
#pragma unroll 4
    for (int w = 0; w < 64; ++w) {
        const float at = cf[wv][w];                     // LDS broadcast
        const float* __restrict__ rowp = &S1h[(wv + w) * OUTD];
        a1 = fmaf(at, rowp[lane], a1);
        a2 = fmaf(at, rowp[o2],   a2);
    }
    pred[(size_t)r * OUTD + lane] = sigmoidf_(a1 + b1[lane]);
    if (lane < 24)
        pred[(size_t)r * OUTD + 64 + lane] = sigmoidf_(a2 + b1[64 + lane]);
}

extern "C" void kernel_launch(void* const* d_in, const int* in_sizes, int n_in,
                              void* d_out, int out_size, void* d_ws, size_t ws_size,
                              hipStream_t stream) {
    const float* spec   = (const float*)d_in[0];
    const float* W_h    = (const float*)d_in[1];
    const float* W_e    = (const float*)d_in[2];
    const float* b_attn = (const float*)d_in[3];
    const float* v_w    = (const float*)d_in[4];
    const float* W1     = (const float*)d_in[5];
    const float* b1     = (const float*)d_in[6];

    const int n_rows = BB * TT;                       // 8192
    char* ws = (char*)d_ws;
    float*        H   = (float*)ws;                   // 4 MB (CTANH-scaled)
    unsigned int* Ebf = (unsigned int*)(ws + ((size_t)4 << 20));  // 2 MB bf16
    float*        S1  = (float*)(ws + ((size_t)6 << 20));         // 2.875 MB

    float* pred  = (float*)d_out;                     // 8192*88
    float* a_out = pred + (size_t)n_rows * OUTD;      // 8192*61

    k_he   <<<n_rows / ROWS_HE, 384, 0, stream>>>(spec, W_h, W_e, W1, b_attn,
                                                  H, Ebf, S1);
    k_fused<<<n_rows / ROWS_F,  512, 0, stream>>>(H, Ebf, v_w, S1, b1,
                                                  pred, a_out);
}

// Round 16
// 75.584 us; speedup vs baseline: 2.8815x; 2.8815x over previous
//
#include <hip/hip_runtime.h>
#include <math.h>

#define N_BINS 229
#define MODEL  128
#define OUTD   88
#define WSZ    30
#define WLEN   61
#define BB     4
#define TT     2048
#define CTANH  2.8853900817779268f   // 2*log2(e)

#define ROWS_HE 8
#define SPAD    232                  // padded spec row stride (floats)
#define ROWS_F  8                    // rows per fused block (1 wave per row)
#define FHALO   71                   // hi = wv + w, wv<8, w<64 -> 0..70
#define EPADU   68                   // u32 stride per E halo row

__device__ __forceinline__ float sigmoidf_(float x) {
    return __builtin_amdgcn_rcpf(1.0f + __expf(-x));
}

// ---- Pass 1: H=(spec@W_h+b)*C ; Ebf=bf16(spec@W_e*C) ; S1=spec@W1 ----
// Round-12-exact (proven ~41 us, spill-free): 384 threads, 8 rows/block,
// per-thread W column loads with 8-deep register prefetch.
__global__ __launch_bounds__(384, 8) void k_he(
        const float* __restrict__ spec,
        const float* __restrict__ W_h,
        const float* __restrict__ W_e,
        const float* __restrict__ W1,
        const float* __restrict__ b_attn,
        float* __restrict__ H,
        unsigned int* __restrict__ Ebf,
        float* __restrict__ S1) {
    const int nb  = blockIdx.x;
    const int tid = threadIdx.x;
    __shared__ float s[ROWS_HE * SPAD];                // 7424 B, zero-padded tail
    const float* __restrict__ base = spec + (size_t)nb * (ROWS_HE * N_BINS);
#pragma unroll
    for (int r = 0; r < ROWS_HE; ++r) {
        if (tid < SPAD)
            s[r * SPAD + tid] = (tid < N_BINS) ? base[r * N_BINS + tid] : 0.0f;
    }
    __syncthreads();

    const float* __restrict__ Wp;
    int st, m = 0;
    float bias = 0.0f;
    if (tid < 128)      { m = tid;       Wp = W_h + m; st = MODEL; bias = b_attn[m]; }
    else if (tid < 256) { m = tid - 128; Wp = W_e + m; st = MODEL; }
    else                { m = tid - 256; Wp = W1 + (m < OUTD ? m : 0); st = OUTD; }

    float acc[ROWS_HE];
#pragma unroll
    for (int r = 0; r < ROWS_HE; ++r) acc[r] = 0.0f;

    float cur[8];
#pragma unroll
    for (int j = 0; j < 8; ++j) cur[j] = Wp[j * st];

    for (int batch = 0; batch < 29; ++batch) {         // 29*8 = 232 (padded)
        const int fb = batch * 8;
        float nxt[8];
        if (batch < 28) {
#pragma unroll
            for (int j = 0; j < 8; ++j) {
                const int f = fb + 8 + j;
                nxt[j] = (f < N_BINS) ? Wp[f * st] : 0.0f;   // tail W = 0
            }
        }
#pragma unroll
        for (int r = 0; r < ROWS_HE; ++r) {
            const float4 sa = *(const float4*)&s[r * SPAD + fb];
            const float4 sb = *(const float4*)&s[r * SPAD + fb + 4];
            acc[r] = fmaf(sa.x, cur[0], acc[r]);
            acc[r] = fmaf(sa.y, cur[1], acc[r]);
            acc[r] = fmaf(sa.z, cur[2], acc[r]);
            acc[r] = fmaf(sa.w, cur[3], acc[r]);
            acc[r] = fmaf(sb.x, cur[4], acc[r]);
            acc[r] = fmaf(sb.y, cur[5], acc[r]);
            acc[r] = fmaf(sb.z, cur[6], acc[r]);
            acc[r] = fmaf(sb.w, cur[7], acc[r]);
        }
        if (batch < 28) {
#pragma unroll
            for (int j = 0; j < 8; ++j) cur[j] = nxt[j];
        }
    }

    const int rg0 = nb * ROWS_HE;
    if (tid < 128) {
#pragma unroll
        for (int r = 0; r < ROWS_HE; ++r)
            H[(size_t)(rg0 + r) * MODEL + m] = (acc[r] + bias) * CTANH;
    } else if (tid < 256) {
#pragma unroll
        for (int r = 0; r < ROWS_HE; ++r) {
            const float val = acc[r] * CTANH;              // pre-scaled E
            const float pv  = __shfl_xor(val, 1, 64);
            if ((m & 1) == 0) {                            // even m packs (m, m+1)
                const unsigned int lo = (__float_as_uint(val) + 0x8000u) >> 16;
                const unsigned int hi = (__float_as_uint(pv) + 0x8000u) & 0xFFFF0000u;
                Ebf[(size_t)(rg0 + r) * 64 + (m >> 1)] = hi | lo;
            }
        }
    } else if (tid < 256 + OUTD) {
#pragma unroll
        for (int r = 0; r < ROWS_HE; ++r)
            S1[(size_t)(rg0 + r) * OUTD + m] = acc[r];     // b1 added later
    }
}

// ---- Pass 2 (fused): scores + softmax + 88-dim pooling + sigmoid ----
// r11 structure; __launch_bounds__(512,4) -> VGPR cap 128, NO spills
// (r11's (512,8) squeezed VGPR to 32 and spilled ~150MB to scratch).
// 1024 blocks, LDS 33.7 KB -> up to 4 blocks/CU if VGPR <= 64.
__global__ __launch_bounds__(512, 4) void k_fused(
        const float* __restrict__ H,
        const unsigned int* __restrict__ Ebf,
        const float* __restrict__ v_w,
        const float* __restrict__ S1,
        const float* __restrict__ b1,
        float* __restrict__ pred,
        float* __restrict__ a_out) {
    const int nb   = blockIdx.x;
    const int tid  = threadIdx.x;
    const int wv   = tid >> 6;              // 0..7 = local row
    const int lane = tid & 63;
    const int r0   = nb * ROWS_F;
    const int b    = r0 >> 11;              // T = 2048
    const int t0   = r0 & (TT - 1);
    const int r    = r0 + wv;
    const int t    = t0 + wv;

    __shared__ __align__(16) unsigned char ubuf[FHALO * OUTD * 4];  // 24992 B
    unsigned int* Ebs = (unsigned int*)ubuf;        // [FHALO][EPADU]
    float*        S1h = (float*)ubuf;               // [FHALO][88]
    __shared__ float4 Hs4[ROWS_F * 32];             //  4096 B
    __shared__ float4 Vs4[32];                      //   512 B
    __shared__ float  scA[ROWS_F][64];              //  2048 B
    __shared__ float  cf[ROWS_F][64];               //  2048 B (total ~33.7 KB)

    // ---- stage bf16 E halo (zero outside [0,TT) == reference zero-pad) ----
    const uint4* __restrict__ Eb16 = (const uint4*)Ebf + (size_t)b * TT * 16;
    for (int i = tid; i < FHALO * 16; i += 512) {
        const int row = i >> 4, c = i & 15;
        const int s   = t0 - WSZ + row;
        uint4 v = make_uint4(0u, 0u, 0u, 0u);
        if (s >= 0 && s < TT) v = Eb16[(size_t)s * 16 + c];
        *(uint4*)&Ebs[row * EPADU + (c << 2)] = v;
    }
    if (tid < ROWS_F * 32)
        Hs4[tid] = ((const float4*)H)[(size_t)r0 * 32 + tid];
    else if (tid < ROWS_F * 32 + 32)
        Vs4[tid - ROWS_F * 32] = ((const float4*)v_w)[tid - ROWS_F * 32];
    __syncthreads();

    const int g  = lane & 3;
    const int w0 = lane >> 2;

    // ---- Sum(v_w), hoisted ----
    float vs = 0.f;
#pragma unroll
    for (int q = 0; q < 8; ++q) {
        const float4 vq = Vs4[(q << 2) + g];
        vs += (vq.x + vq.y) + (vq.z + vq.w);
    }
    vs += __shfl_xor(vs, 1, 64);
    vs += __shfl_xor(vs, 2, 64);

    // ---- scores for row wv ----
    int ro[4];
#pragma unroll
    for (int it = 0; it < 4; ++it)
        ro[it] = (wv + w0 + it * 16) * EPADU;       // hi in [0,70]

    const float4* __restrict__ HsR = &Hs4[wv * 32];

    float pp[4] = {0.f, 0.f, 0.f, 0.f};
#pragma unroll
    for (int q = 0; q < 8; ++q) {
        const int    cq = (q << 2) + g;
        const float4 hq = HsR[cq];          // pre-scaled by CTANH
        const float4 vq = Vs4[cq];
        const float nx = -2.f * vq.x, ny = -2.f * vq.y,
                    nz = -2.f * vq.z, nw = -2.f * vq.w;
#pragma unroll
        for (int it = 0; it < 4; ++it) {
            const uint2 e2 = *(const uint2*)&Ebs[ro[it] + (cq << 1)];
            const float f0 = __uint_as_float(e2.x << 16);
            const float f1 = __uint_as_float(e2.x & 0xFFFF0000u);
            const float f2 = __uint_as_float(e2.y << 16);
            const float f3 = __uint_as_float(e2.y & 0xFFFF0000u);
            float u;
            u = __builtin_amdgcn_rcpf(__builtin_amdgcn_exp2f(f0 + hq.x) + 1.f);
            pp[it] = fmaf(nx, u, pp[it]);
            u = __builtin_amdgcn_rcpf(__builtin_amdgcn_exp2f(f1 + hq.y) + 1.f);
            pp[it] = fmaf(ny, u, pp[it]);
            u = __builtin_amdgcn_rcpf(__builtin_amdgcn_exp2f(f2 + hq.z) + 1.f);
            pp[it] = fmaf(nz, u, pp[it]);
            u = __builtin_amdgcn_rcpf(__builtin_amdgcn_exp2f(f3 + hq.w) + 1.f);
            pp[it] = fmaf(nw, u, pp[it]);
        }
    }
#pragma unroll
    for (int it = 0; it < 4; ++it) {
        float p = pp[it];
        p += __shfl_xor(p, 1, 64);
        p += __shfl_xor(p, 2, 64);
        const int w = w0 + it * 16;
        if (g == 0 && w < WLEN) scA[wv][w] = p + vs;
    }

    // ---- wave-local softmax (same wave wrote scA[wv]) ----
    {
        float x = (lane < WLEN) ? scA[wv][lane] : -INFINITY;
        float mx = x;
#pragma unroll
        for (int d = 32; d >= 1; d >>= 1) mx = fmaxf(mx, __shfl_xor(mx, d, 64));
        float e = (lane < WLEN) ? __expf(x - mx) : 0.0f;
        float sm = e;
#pragma unroll
        for (int d = 32; d >= 1; d >>= 1) sm += __shfl_xor(sm, d, 64);
        const float a = e * __builtin_amdgcn_rcpf(sm);
        if (lane < WLEN) a_out[(size_t)r * WLEN + lane] = a;
        const int sl = t + lane - WSZ;
        cf[wv][lane] = (lane < WLEN && sl >= 0 && sl < TT) ? a : 0.0f;
    }

    __syncthreads();                        // all waves done reading Ebs

    // ---- re-stage union with S1 halo (zero outside [0,TT)) ----
    const float4* __restrict__ Sb4 = (const float4*)S1 + (size_t)b * TT * 22;
    for (int i = tid; i < FHALO * 22; i += 512) {
        const int row = i / 22, c = i - row * 22;
        const int s   = t0 - WSZ + row;
        float4 v = make_float4(0.f, 0.f, 0.f, 0.f);
        if (s >= 0 && s < TT) v = Sb4[(size_t)s * 22 + c];
        *(float4*)&S1h[row * OUTD + (c << 2)] = v;
    }
    __syncthreads();

    // ---- pooling row wv: pred[t] = sigmoid(sum_w cf[w]*S1h[wv+w] + b1) ----
    const int o2 = 64 + (lane < 24 ? lane : 23);
    float a1 = 0.f, a2 = 0.f;
#pragma unroll 4
    for (int w = 0; w < 64; ++w) {
        const float at = cf[wv][w];                     // LDS broadcast
        const float* __restrict__ rowp = &S1h[(wv + w) * OUTD];
        a1 = fmaf(at, rowp[lane], a1);
        a2 = fmaf(at, rowp[o2],   a2);
    }
    pred[(size_t)r * OUTD + lane] = sigmoidf_(a1 + b1[lane]);
    if (lane < 24)
        pred[(size_t)r * OUTD + 64 + lane] = sigmoidf_(a2 + b1[64 + lane]);
}

extern "C" void kernel_launch(void* const* d_in, const int* in_sizes, int n_in,
                              void* d_out, int out_size, void* d_ws, size_t ws_size,
                              hipStream_t stream) {
    const float* spec   = (const float*)d_in[0];
    const float* W_h    = (const float*)d_in[1];
    const float* W_e    = (const float*)d_in[2];
    const float* b_attn = (const float*)d_in[3];
    const float* v_w    = (const float*)d_in[4];
    const float* W1     = (const float*)d_in[5];
    const float* b1     = (const float*)d_in[6];

    const int n_rows = BB * TT;                       // 8192
    char* ws = (char*)d_ws;
    float*        H   = (float*)ws;                   // 4 MB (CTANH-scaled)
    unsigned int* Ebf = (unsigned int*)(ws + ((size_t)4 << 20));  // 2 MB bf16
    float*        S1  = (float*)(ws + ((size_t)6 << 20));         // 2.875 MB

    float* pred  = (float*)d_out;                     // 8192*88
    float* a_out = pred + (size_t)n_rows * OUTD;      // 8192*61

    k_he   <<<n_rows / ROWS_HE, 384, 0, stream>>>(spec, W_h, W_e, W1, b_attn,
                                                  H, Ebf, S1);
    k_fused<<<n_rows / ROWS_F,  512, 0, stream>>>(H, Ebf, v_w, S1, b1,
                                                  pred, a_out);
}

// Round 17
// 53.733 us; speedup vs baseline: 4.0534x; 1.4067x over previous
//
#include <hip/hip_runtime.h>
#include <math.h>

#define N_BINS 229
#define MODEL  128
#define OUTD   88
#define WSZ    30
#define WLEN   61
#define BB     4
#define TT     2048
#define CTANH  2.8853900817779268f   // 2*log2(e)

#define KPAD   256                   // padded K (229 -> 256 = 8 x 32)
#define NPAD   384                   // padded N (H 128 | E 128 | S1 88 | pad)
#define BSTRB  80                    // LDS row stride bytes (40 bf16, 16B-mult)
#define ROWS_F 8
#define FHALO  71
#define EPADU  68

typedef __attribute__((ext_vector_type(8))) short  short8v;  // 8 bf16 (4 VGPR)
typedef __attribute__((ext_vector_type(4))) float  f32x4;

__device__ __forceinline__ unsigned short bf16_rne(float x) {
    unsigned int u = __float_as_uint(x);
    return (unsigned short)((u + 0x7FFFu + ((u >> 16) & 1u)) >> 16);
}
__device__ __forceinline__ float sigmoidf_(float x) {
    return __builtin_amdgcn_rcpf(1.0f + __expf(-x));
}

// ---- Prep: Wt[n][k] = bf16 of (W_h*C | W_e*C | W1)^T, zero-padded ----
__global__ __launch_bounds__(256) void k_prep_w(
        const float* __restrict__ W_h, const float* __restrict__ W_e,
        const float* __restrict__ W1, unsigned short* __restrict__ Wt) {
    const int n = blockIdx.x;        // 0..383
    const int k = threadIdx.x;       // 0..255
    float v = 0.0f;
    if (k < N_BINS) {
        if (n < 128)      v = W_h[k * MODEL + n] * CTANH;
        else if (n < 256) v = W_e[k * MODEL + (n - 128)] * CTANH;
        else if (n < 344) v = W1[k * OUTD + (n - 256)];
    }
    Wt[n * KPAD + k] = bf16_rne(v);
}

// ---- Pass 1 (MFMA GEMM): [8192 x 229] @ [229 x 344] -> H, Ebf, S1 ----
// BM=16, full N per block (24 tiles of 16, 8 waves x 3 tiles). A (spec) is
// converted fp32->bf16 hi+lo in-kernel (2 MFMA/tile: removes A-side rounding).
// D layout (verified): D[(lane>>4)*4 + r][lane&15].
__global__ __launch_bounds__(512, 4) void k_he_mfma(
        const float* __restrict__ spec,
        const unsigned short* __restrict__ Wt,
        const float* __restrict__ b_attn,
        float* __restrict__ H,
        unsigned int* __restrict__ Ebf,
        float* __restrict__ S1) {
    __shared__ __align__(16) unsigned char lds[NPAD * BSTRB + 2 * 16 * BSTRB];
    unsigned char* Bl  = lds;                         // [384][80B]
    unsigned char* Ahi = lds + NPAD * BSTRB;          // [16][80B]
    unsigned char* Alo = Ahi + 16 * BSTRB;            // [16][80B]

    const int tid   = threadIdx.x;
    const int gm0   = blockIdx.x * 16;
    const int lane  = tid & 63;
    const int wv    = tid >> 6;          // 0..7
    const int mfrag = lane & 15;
    const int kg    = lane >> 4;         // 0..3

    f32x4 acc0 = {0,0,0,0}, acc1 = {0,0,0,0}, acc2 = {0,0,0,0};
    const uint4* __restrict__ Wt4 = (const uint4*)Wt;

    for (int kb = 0; kb < 8; ++kb) {
        __syncthreads();                 // protect LDS from previous reads
        // ---- stage B K-slice: 384 rows x 64 B (1536 x 16B units) ----
#pragma unroll
        for (int it = 0; it < 3; ++it) {
            const int u = it * 512 + tid;
            const int row = u >> 2, q = u & 3;
            const uint4 v = Wt4[row * 32 + kb * 4 + q];
            *(uint4*)(Bl + row * BSTRB + q * 16) = v;
        }
        // ---- stage A tile: 16 rows x 32 k, fp32 -> bf16 hi+lo ----
        if (tid < 256) {
            const int row = tid >> 4, kp = tid & 15;
            const int gk  = kb * 32 + kp * 2;
            const float* __restrict__ sp = spec + (size_t)(gm0 + row) * N_BINS;
            const float v0 = (gk     < N_BINS) ? sp[gk]     : 0.0f;
            const float v1 = (gk + 1 < N_BINS) ? sp[gk + 1] : 0.0f;
            const unsigned short h0 = bf16_rne(v0), h1 = bf16_rne(v1);
            const float r0 = v0 - __uint_as_float((unsigned int)h0 << 16);
            const float r1 = v1 - __uint_as_float((unsigned int)h1 << 16);
            *(unsigned int*)(Ahi + row * BSTRB + kp * 4) =
                (unsigned int)h0 | ((unsigned int)h1 << 16);
            *(unsigned int*)(Alo + row * BSTRB + kp * 4) =
                (unsigned int)bf16_rne(r0) | ((unsigned int)bf16_rne(r1) << 16);
        }
        __syncthreads();

        const short8v ah = *(const short8v*)(Ahi + mfrag * BSTRB + kg * 16);
        const short8v al = *(const short8v*)(Alo + mfrag * BSTRB + kg * 16);
        const int n0 = wv * 48;
        const short8v b0 = *(const short8v*)(Bl + (n0      + mfrag) * BSTRB + kg * 16);
        const short8v b1 = *(const short8v*)(Bl + (n0 + 16 + mfrag) * BSTRB + kg * 16);
        const short8v b2 = *(const short8v*)(Bl + (n0 + 32 + mfrag) * BSTRB + kg * 16);
        acc0 = __builtin_amdgcn_mfma_f32_16x16x32_bf16(ah, b0, acc0, 0, 0, 0);
        acc0 = __builtin_amdgcn_mfma_f32_16x16x32_bf16(al, b0, acc0, 0, 0, 0);
        acc1 = __builtin_amdgcn_mfma_f32_16x16x32_bf16(ah, b1, acc1, 0, 0, 0);
        acc1 = __builtin_amdgcn_mfma_f32_16x16x32_bf16(al, b1, acc1, 0, 0, 0);
        acc2 = __builtin_amdgcn_mfma_f32_16x16x32_bf16(ah, b2, acc2, 0, 0, 0);
        acc2 = __builtin_amdgcn_mfma_f32_16x16x32_bf16(al, b2, acc2, 0, 0, 0);
    }

    // ---- epilogue: route tiles to H / Ebf / S1 ----
#pragma unroll
    for (int t = 0; t < 3; ++t) {
        const f32x4 acc = (t == 0) ? acc0 : (t == 1) ? acc1 : acc2;
        const int gn = wv * 48 + t * 16 + mfrag;     // region uniform per tile
        if (gn < 128) {
            const float bc = b_attn[gn] * CTANH;
#pragma unroll
            for (int r = 0; r < 4; ++r) {
                const int gm = gm0 + (kg << 2) + r;
                H[(size_t)gm * MODEL + gn] = acc[r] + bc;
            }
        } else if (gn < 256) {
            const int ne = gn - 128;
#pragma unroll
            for (int r = 0; r < 4; ++r) {
                const float own = acc[r];
                const float pv  = __shfl_xor(own, 1, 64);
                if ((ne & 1) == 0) {
                    const int gm = gm0 + (kg << 2) + r;
                    Ebf[(size_t)gm * 64 + (ne >> 1)] =
                        (unsigned int)bf16_rne(own) |
                        ((unsigned int)bf16_rne(pv) << 16);
                }
            }
        } else if (gn < 344) {
            const int ns = gn - 256;
#pragma unroll
            for (int r = 0; r < 4; ++r) {
                const int gm = gm0 + (kg << 2) + r;
                S1[(size_t)gm * OUTD + ns] = acc[r];
            }
        }
    }
}

// ---- Pass 2 (fused, round-16-exact): scores + softmax + pooling + sigmoid ----
__global__ __launch_bounds__(512, 4) void k_fused(
        const float* __restrict__ H,
        const unsigned int* __restrict__ Ebf,
        const float* __restrict__ v_w,
        const float* __restrict__ S1,
        const float* __restrict__ b1,
        float* __restrict__ pred,
        float* __restrict__ a_out) {
    const int nb   = blockIdx.x;
    const int tid  = threadIdx.x;
    const int wv   = tid >> 6;              // 0..7 = local row
    const int lane = tid & 63;
    const int r0   = nb * ROWS_F;
    const int b    = r0 >> 11;              // T = 2048
    const int t0   = r0 & (TT - 1);
    const int r    = r0 + wv;
    const int t    = t0 + wv;

    __shared__ __align__(16) unsigned char ubuf[FHALO * OUTD * 4];  // 24992 B
    unsigned int* Ebs = (unsigned int*)ubuf;        // [FHALO][EPADU]
    float*        S1h = (float*)ubuf;               // [FHALO][88]
    __shared__ float4 Hs4[ROWS_F * 32];             //  4096 B
    __shared__ float4 Vs4[32];                      //   512 B
    __shared__ float  scA[ROWS_F][64];              //  2048 B
    __shared__ float  cf[ROWS_F][64];               //  2048 B

    const uint4* __restrict__ Eb16 = (const uint4*)Ebf + (size_t)b * TT * 16;
    for (int i = tid; i < FHALO * 16; i += 512) {
        const int row = i >> 4, c = i & 15;
        const int s   = t0 - WSZ + row;
        uint4 v = make_uint4(0u, 0u, 0u, 0u);
        if (s >= 0 && s < TT) v = Eb16[(size_t)s * 16 + c];
        *(uint4*)&Ebs[row * EPADU + (c << 2)] = v;
    }
    if (tid < ROWS_F * 32)
        Hs4[tid] = ((const float4*)H)[(size_t)r0 * 32 + tid];
    else if (tid < ROWS_F * 32 + 32)
        Vs4[tid - ROWS_F * 32] = ((const float4*)v_w)[tid - ROWS_F * 32];
    __syncthreads();

    const int g  = lane & 3;
    const int w0 = lane >> 2;

    float vs = 0.f;
#pragma unroll
    for (int q = 0; q < 8; ++q) {
        const float4 vq = Vs4[(q << 2) + g];
        vs += (vq.x + vq.y) + (vq.z + vq.w);
    }
    vs += __shfl_xor(vs, 1, 64);
    vs += __shfl_xor(vs, 2, 64);

    int ro[4];
#pragma unroll
    for (int it = 0; it < 4; ++it)
        ro[it] = (wv + w0 + it * 16) * EPADU;

    const float4* __restrict__ HsR = &Hs4[wv * 32];

    float pp[4] = {0.f, 0.f, 0.f, 0.f};
#pragma unroll
    for (int q = 0; q < 8; ++q) {
        const int    cq = (q << 2) + g;
        const float4 hq = HsR[cq];
        const float4 vq = Vs4[cq];
        const float nx = -2.f * vq.x, ny = -2.f * vq.y,
                    nz = -2.f * vq.z, nw = -2.f * vq.w;
#pragma unroll
        for (int it = 0; it < 4; ++it) {
            const uint2 e2 = *(const uint2*)&Ebs[ro[it] + (cq << 1)];
            const float f0 = __uint_as_float(e2.x << 16);
            const float f1 = __uint_as_float(e2.x & 0xFFFF0000u);
            const float f2 = __uint_as_float(e2.y << 16);
            const float f3 = __uint_as_float(e2.y & 0xFFFF0000u);
            float u;
            u = __builtin_amdgcn_rcpf(__builtin_amdgcn_exp2f(f0 + hq.x) + 1.f);
            pp[it] = fmaf(nx, u, pp[it]);
            u = __builtin_amdgcn_rcpf(__builtin_amdgcn_exp2f(f1 + hq.y) + 1.f);
            pp[it] = fmaf(ny, u, pp[it]);
            u = __builtin_amdgcn_rcpf(__builtin_amdgcn_exp2f(f2 + hq.z) + 1.f);
            pp[it] = fmaf(nz, u, pp[it]);
            u = __builtin_amdgcn_rcpf(__builtin_amdgcn_exp2f(f3 + hq.w) + 1.f);
            pp[it] = fmaf(nw, u, pp[it]);
        }
    }
#pragma unroll
    for (int it = 0; it < 4; ++it) {
        float p = pp[it];
        p += __shfl_xor(p, 1, 64);
        p += __shfl_xor(p, 2, 64);
        const int w = w0 + it * 16;
        if (g == 0 && w < WLEN) scA[wv][w] = p + vs;
    }

    {
        float x = (lane < WLEN) ? scA[wv][lane] : -INFINITY;
        float mx = x;
#pragma unroll
        for (int d = 32; d >= 1; d >>= 1) mx = fmaxf(mx, __shfl_xor(mx, d, 64));
        float e = (lane < WLEN) ? __expf(x - mx) : 0.0f;
        float sm = e;
#pragma unroll
        for (int d = 32; d >= 1; d >>= 1) sm += __shfl_xor(sm, d, 64);
        const float a = e * __builtin_amdgcn_rcpf(sm);
        if (lane < WLEN) a_out[(size_t)r * WLEN + lane] = a;
        const int sl = t + lane - WSZ;
        cf[wv][lane] = (lane < WLEN && sl >= 0 && sl < TT) ? a : 0.0f;
    }

    __syncthreads();

    const float4* __restrict__ Sb4 = (const float4*)S1 + (size_t)b * TT * 22;
    for (int i = tid; i < FHALO * 22; i += 512) {
        const int row = i / 22, c = i - row * 22;
        const int s   = t0 - WSZ + row;
        float4 v = make_float4(0.f, 0.f, 0.f, 0.f);
        if (s >= 0 && s < TT) v = Sb4[(size_t)s * 22 + c];
        *(float4*)&S1h[row * OUTD + (c << 2)] = v;
    }
    __syncthreads();

    const int o2 = 64 + (lane < 24 ? lane : 23);
    float a1 = 0.f, a2 = 0.f;
#pragma unroll 4
    for (int w = 0; w < 64; ++w) {
        const float at = cf[wv][w];
        const float* __restrict__ rowp = &S1h[(wv + w) * OUTD];
        a1 = fmaf(at, rowp[lane], a1);
        a2 = fmaf(at, rowp[o2],   a2);
    }
    pred[(size_t)r * OUTD + lane] = sigmoidf_(a1 + b1[lane]);
    if (lane < 24)
        pred[(size_t)r * OUTD + 64 + lane] = sigmoidf_(a2 + b1[64 + lane]);
}

extern "C" void kernel_launch(void* const* d_in, const int* in_sizes, int n_in,
                              void* d_out, int out_size, void* d_ws, size_t ws_size,
                              hipStream_t stream) {
    const float* spec   = (const float*)d_in[0];
    const float* W_h    = (const float*)d_in[1];
    const float* W_e    = (const float*)d_in[2];
    const float* b_attn = (const float*)d_in[3];
    const float* v_w    = (const float*)d_in[4];
    const float* W1     = (const float*)d_in[5];
    const float* b1     = (const float*)d_in[6];

    const int n_rows = BB * TT;                       // 8192
    char* ws = (char*)d_ws;
    float*          H   = (float*)ws;                               // 4 MB
    unsigned int*   Ebf = (unsigned int*)(ws + ((size_t)4 << 20));  // 2 MB
    float*          S1  = (float*)(ws + ((size_t)6 << 20));         // 2.875 MB
    unsigned short* Wt  = (unsigned short*)(ws + ((size_t)9 << 20)); // 192 KB

    float* pred  = (float*)d_out;                     // 8192*88
    float* a_out = pred + (size_t)n_rows * OUTD;      // 8192*61

    k_prep_w <<<NPAD,         256, 0, stream>>>(W_h, W_e, W1, Wt);
    k_he_mfma<<<n_rows / 16,  512, 0, stream>>>(spec, Wt, b_attn, H, Ebf, S1);
    k_fused  <<<n_rows / ROWS_F, 512, 0, stream>>>(H, Ebf, v_w, S1, b1,
                                                   pred, a_out);
}